// Round 2
// baseline (1024.438 us; speedup 1.0000x reference)
//
#include <hip/hip_runtime.h>

// PolicyNetGARCH: B=1024 S=512 OBS=5 NINS=2 H=32 NBLK=4
// Design: 1 WG (4 waves) per batch element. Wave k = LSTM block k, weights
// in VGPRs as packed f16 pairs, software-pipelined over waves, xt handoff via
// LDS double-buffered slots, acts broadcast to SGPRs via readlane, dots via
// v_dot2_f32_f16 (f32 accumulate).

constexpr int B_ = 1024, S_ = 512, OBS_ = 5, NINS_ = 2, H_ = 32, NBLK_ = 4;
constexpr float EPS_ = 1e-6f;

// NOTE: clang's amdgcn builtins (cvt_pkrtz, fdot2) use __fp16-based vectors.
typedef __fp16 half2_t __attribute__((ext_vector_type(2)));

__device__ __forceinline__ float rcp_(float x) { return __builtin_amdgcn_rcpf(x); }
__device__ __forceinline__ float rsq_(float x) { return __builtin_amdgcn_rsqf(x); }

__device__ __forceinline__ float dot2_(half2_t a, half2_t b, float c) {
#if __has_builtin(__builtin_amdgcn_fdot2)
  return __builtin_amdgcn_fdot2(a, b, c, false);
#else
  return c + (float)a[0] * (float)b[0] + (float)a[1] * (float)b[1];
#endif
}

__device__ __forceinline__ half2_t pk_(float a, float b) {
#if __has_builtin(__builtin_amdgcn_cvt_pkrtz)
  return __builtin_amdgcn_cvt_pkrtz(a, b);
#else
  half2_t r; r[0] = (__fp16)a; r[1] = (__fp16)b; return r;
#endif
}

__global__ __launch_bounds__(256, 2) void garch_pipeline_kernel(
    const float* __restrict__ obs, const float* __restrict__ prev,
    const float* __restrict__ W_in, const float* __restrict__ b_in,
    const float* __restrict__ rms_w,
    const float* __restrict__ W_ih, const float* __restrict__ W_hh,
    const float* __restrict__ b_ih, const float* __restrict__ b_hh,
    const float* __restrict__ head_w, const float* __restrict__ head_b,
    float* __restrict__ out) {
  const int b    = blockIdx.x;
  const int tid  = threadIdx.x;
  const int k    = tid >> 6;    // wave id == LSTM block index
  const int lane = tid & 63;
  const int hl   = lane & 31;   // H-unit (mirrored in high half-wave)
  const bool low = (lane < 32);

  // handoff slots: slot[j] carries xt from wave j to wave j+1, parity dbuf
  __shared__ float slot[3][2][H_];

  // ---- init: per-lane weights (rows lane and lane+64 of block k), f16 packed.
  // Packed reg t: t<16 -> W_ih cols 2t,2t+1 ; t>=16 -> W_hh cols 2(t-16),...
  half2_t w0[32], w1[32];
  {
    const float2* Wih0 = (const float2*)(W_ih + (size_t)k * 128 * 32 + (size_t)lane * 32);
    const float2* Wih1 = (const float2*)(W_ih + (size_t)k * 128 * 32 + (size_t)(lane + 64) * 32);
    const float2* Whh0 = (const float2*)(W_hh + (size_t)k * 128 * 32 + (size_t)lane * 32);
    const float2* Whh1 = (const float2*)(W_hh + (size_t)k * 128 * 32 + (size_t)(lane + 64) * 32);
#pragma unroll
    for (int t = 0; t < 16; ++t) {
      float2 a = Wih0[t], c2 = Whh0[t], d2 = Wih1[t], e2 = Whh1[t];
      w0[t]      = pk_(a.x, a.y);
      w0[16 + t] = pk_(c2.x, c2.y);
      w1[t]      = pk_(d2.x, d2.y);
      w1[16 + t] = pk_(e2.x, e2.y);
    }
  }
  const float bias0 = b_ih[k * 128 + lane]      + b_hh[k * 128 + lane];
  const float bias1 = b_ih[k * 128 + lane + 64] + b_hh[k * 128 + lane + 64];
  const float rw    = rms_w[k * 32 + hl];

  // wave 0: input projection weights; wave 3: head weights
  float win[7]; float bi = 0.f;
  float hw0 = 0.f, hw1 = 0.f, hb0 = 0.f, hb1 = 0.f;
  if (k == 0) {
#pragma unroll
    for (int j = 0; j < 7; ++j) win[j] = W_in[hl * 7 + j];
    bi = b_in[hl];
  }
  if (k == 3) {
    hw0 = head_w[hl]; hw1 = head_w[32 + hl];
    hb0 = head_b[0];  hb1 = head_b[1];
  }

  // branchless activation constants for g1: low lanes -> tanh, high -> sigmoid
  const float mC = low ? -2.f : -1.f;
  const float aC = low ?  2.f :  1.f;
  const float dC = low ? -1.f :  0.f;

  // state
  float c  = 0.f;   // cell state (valid in low lanes)
  float hn = 0.f;   // last h_new fp32 (valid in low lanes)
  int s_h[16];      // packed f16 h-state, wave-uniform -> SGPRs
#pragma unroll
  for (int u = 0; u < 16; ++u) s_h[u] = 0;

  // wave-0 input prefetch (double-buffered regs)
  const float* obs_b  = obs  + (size_t)b * S_ * OBS_;
  const float* prev_b = prev + (size_t)b * S_ * NINS_;
  float incur[7], innx[7];
  if (k == 0) {
#pragma unroll
    for (int j = 0; j < 5; ++j) incur[j] = obs_b[j];
    incur[5] = prev_b[0]; incur[6] = prev_b[1];
  }

  float* out_y  = out;                                   // [2][B][S]
  float* out_hT = out + (size_t)NINS_ * B_ * S_;         // [4][B][H]
  float* out_cT = out_hT + (size_t)NBLK_ * B_ * H_;      // [4][B][H]

  for (int tau = 0; tau < S_ + NBLK_ - 1; ++tau) {
    __syncthreads();                 // every thread, every tick
    const int t = tau - k;           // wave-uniform
    if (t < 0 || t >= S_) continue;

    // ---- 1. obtain xt (valid in all 64 lanes) ----
    float xt;
    if (k == 0) {
      if (t + 1 < S_) {              // prefetch next step's inputs
        const float* o2 = obs_b  + (size_t)(t + 1) * OBS_;
        const float* p2 = prev_b + (size_t)(t + 1) * NINS_;
#pragma unroll
        for (int j = 0; j < 5; ++j) innx[j] = o2[j];
        innx[5] = p2[0]; innx[6] = p2[1];
      }
      float acc = bi;
#pragma unroll
      for (int j = 0; j < 7; ++j) acc = fmaf(win[j], incur[j], acc);
      xt = acc;
    } else {
      xt = slot[k - 1][tau & 1][hl];
    }

    // ---- 2. RMSNorm (butterfly over 32-lane halves) ----
    float ms = xt * xt;
#pragma unroll
    for (int m = 1; m <= 16; m <<= 1) ms += __shfl_xor(ms, m);
    const float rinv = rsq_(ms * (1.0f / 32.0f) + EPS_);
    const float xn = xt * rinv * rw;

    // ---- 3. broadcast xn to SGPRs as f16 pairs ----
    const float xn_o = __shfl_xor(xn, 1);
    const int pkxi = __builtin_bit_cast(int, pk_(xn, xn_o)); // valid @ even lanes
    int s_x[16];
#pragma unroll
    for (int u = 0; u < 16; ++u) s_x[u] = __builtin_amdgcn_readlane(pkxi, 2 * u);

    // ---- 4. gate dots: rows (lane) -> a0, (lane+64) -> a1 ----
    float a0 = bias0, a1 = bias1;
#pragma unroll
    for (int u = 0; u < 16; ++u) {
      half2_t hx = __builtin_bit_cast(half2_t, s_x[u]);
      a0 = dot2_(hx, w0[u], a0);
      a1 = dot2_(hx, w1[u], a1);
    }
#pragma unroll
    for (int u = 0; u < 16; ++u) {
      half2_t hh = __builtin_bit_cast(half2_t, s_h[u]);
      a0 = dot2_(hh, w0[16 + u], a0);
      a1 = dot2_(hh, w1[16 + u], a1);
    }

    // ---- 5. activations ----
    // low lane h:  a0 = i_h, a1 = g_h ; high lane h+32: a0 = f_h, a1 = o_h
    const float g0 = rcp_(1.0f + __expf(-a0));                   // sigmoid(i|f)
    const float g1 = fmaf(aC, rcp_(1.0f + __expf(mC * a1)), dC); // tanh(g)|sig(o)
    const float x0 = __shfl_xor(g0, 32);  // low: sigmoid(f)
    const float x1 = __shfl_xor(g1, 32);  // low: sigmoid(o)
    c = x0 * c + g0 * g1;                                        // c_new
    const float tc = fmaf(2.f, rcp_(1.0f + __expf(-2.f * c)), -1.f); // tanh(c)
    hn = x1 * tc;                                                // h_new

    const float xo = xt + hn;  // residual (valid in low lanes)

    // ---- 6. handoff or head ----
    if (k < 3) {
      if (low) slot[k][(tau + 1) & 1][hl] = xo;
    } else {
      float p0 = xo * hw0, p1 = xo * hw1;
#pragma unroll
      for (int m = 1; m <= 16; m <<= 1) {
        p0 += __shfl_xor(p0, m);
        p1 += __shfl_xor(p1, m);
      }
      if (lane == 0) {
        const float r0 = p0 + hb0, r1 = p1 + hb1;
        const float v0 = fminf(__expf(fabsf(r0)) - 1.0f, 5.0f);
        const float v1 = fminf(__expf(fabsf(r1)) - 1.0f, 10.0f);
        out_y[(size_t)b * S_ + t]                      = copysignf(v0, r0);
        out_y[(size_t)B_ * S_ + (size_t)b * S_ + t]    = copysignf(v1, r1);
      }
    }

    // ---- 7. repack h-state to SGPRs ----
    const float hn_o = __shfl_xor(hn, 1);
    const int pkhi = __builtin_bit_cast(int, pk_(hn, hn_o));
#pragma unroll
    for (int u = 0; u < 16; ++u) s_h[u] = __builtin_amdgcn_readlane(pkhi, 2 * u);

    // ---- 8. final states ----
    if (t == S_ - 1 && low) {
      out_hT[((size_t)k * B_ + b) * H_ + hl] = hn;
      out_cT[((size_t)k * B_ + b) * H_ + hl] = c;
    }

    if (k == 0) {
#pragma unroll
      for (int j = 0; j < 7; ++j) incur[j] = innx[j];
    }
  }
}

extern "C" void kernel_launch(void* const* d_in, const int* in_sizes, int n_in,
                              void* d_out, int out_size, void* d_ws, size_t ws_size,
                              hipStream_t stream) {
  (void)in_sizes; (void)n_in; (void)d_ws; (void)ws_size; (void)out_size;
  garch_pipeline_kernel<<<dim3(B_), dim3(256), 0, stream>>>(
      (const float*)d_in[0],  // obs_sequence [B,S,OBS]
      (const float*)d_in[1],  // prev_actions [B,S,NINS]
      (const float*)d_in[2],  // W_in [H, OBS+NINS]
      (const float*)d_in[3],  // b_in [H]
      (const float*)d_in[4],  // rms_w [NBLK,H]
      (const float*)d_in[5],  // W_ih [NBLK,4H,H]
      (const float*)d_in[6],  // W_hh [NBLK,4H,H]
      (const float*)d_in[7],  // b_ih [NBLK,4H]
      (const float*)d_in[8],  // b_hh [NBLK,4H]
      (const float*)d_in[9],  // head_w [NINS,H]
      (const float*)d_in[10], // head_b [NINS]
      (float*)d_out);
}

// Round 3
// 812.189 us; speedup vs baseline: 1.2613x; 1.2613x over previous
//
#include <hip/hip_runtime.h>

// PolicyNetGARCH: B=1024 S=512 OBS=5 NINS=2 H=32 NBLK=4
// 1 WG (4 waves) per batch element; wave k = LSTM block k, weights in VGPRs
// as packed f16 pairs; pipeline skew across waves; xt handoff via LDS slots.
// Round 3: all intra-wave cross-lane ops moved from LDS pipe (ds_swizzle/
// bpermute, ~120cy) to VALU (DPP reduce chains, quad_perm pack,
// permlane32_swap for the lane^32 gate exchange); dot chains split 2-way.

constexpr int B_ = 1024, S_ = 512, OBS_ = 5, NINS_ = 2, H_ = 32, NBLK_ = 4;
constexpr float EPS_ = 1e-6f;

typedef __fp16 half2_t __attribute__((ext_vector_type(2)));

__device__ __forceinline__ float rcp_(float x) { return __builtin_amdgcn_rcpf(x); }
__device__ __forceinline__ float rsq_(float x) { return __builtin_amdgcn_rsqf(x); }

__device__ __forceinline__ float dot2_(half2_t a, half2_t b, float c) {
  return __builtin_amdgcn_fdot2(a, b, c, false);
}

__device__ __forceinline__ half2_t pk_(float a, float b) {
  return __builtin_amdgcn_cvt_pkrtz(a, b);
}

// DPP add step: v += value moved by dpp_ctrl (0 for out-of-bounds lanes).
template <int CTRL>
__device__ __forceinline__ float dppadd_(float v) {
  int m = __builtin_amdgcn_update_dpp(0, __builtin_bit_cast(int, v),
                                      CTRL, 0xF, 0xF, true);
  return v + __builtin_bit_cast(float, m);
}

// Sum over each 32-lane half; returns SGPR-broadcast sum of lanes 0..31.
__device__ __forceinline__ float half_reduce_bcast_(float v) {
  v = dppadd_<0x111>(v);  // row_shr:1
  v = dppadd_<0x112>(v);  // row_shr:2
  v = dppadd_<0x114>(v);  // row_shr:4
  v = dppadd_<0x118>(v);  // row_shr:8
  v = dppadd_<0x142>(v);  // row_bcast:15 -> lane31 = sum(0..31)
  int s = __builtin_amdgcn_readlane(__builtin_bit_cast(int, v), 31);
  return __builtin_bit_cast(float, s);
}

// Value held by lane^32, valid in LOW lanes (high-lane result unused).
__device__ __forceinline__ float swap32_low_(float v) {
#if __has_builtin(__builtin_amdgcn_permlane32_swap)
  auto r = __builtin_amdgcn_permlane32_swap(
      __builtin_bit_cast(int, v), __builtin_bit_cast(int, v), false, false);
  return __builtin_bit_cast(float, (int)r[1]);
#else
  return __shfl_xor(v, 32);
#endif
}

// quad_perm(1,0,3,2): neighbor-pair exchange (lane^1) as 1 VALU op.
__device__ __forceinline__ float pairswap_(float v) {
  int m = __builtin_amdgcn_update_dpp(0, __builtin_bit_cast(int, v),
                                      0xB1, 0xF, 0xF, true);
  return __builtin_bit_cast(float, m);
}

__global__ __launch_bounds__(256, 2) void garch_pipeline_kernel(
    const float* __restrict__ obs, const float* __restrict__ prev,
    const float* __restrict__ W_in, const float* __restrict__ b_in,
    const float* __restrict__ rms_w,
    const float* __restrict__ W_ih, const float* __restrict__ W_hh,
    const float* __restrict__ b_ih, const float* __restrict__ b_hh,
    const float* __restrict__ head_w, const float* __restrict__ head_b,
    float* __restrict__ out) {
  const int b    = blockIdx.x;
  const int tid  = threadIdx.x;
  const int k    = tid >> 6;    // wave id == LSTM block index
  const int lane = tid & 63;
  const int hl   = lane & 31;   // H-unit (mirrored in high half-wave)
  const bool low = (lane < 32);

  __shared__ float slot[3][2][H_];

  // per-lane weights: rows (lane) and (lane+64) of block k, packed f16 pairs
  half2_t w0[32], w1[32];
  {
    const float2* Wih0 = (const float2*)(W_ih + (size_t)k * 128 * 32 + (size_t)lane * 32);
    const float2* Wih1 = (const float2*)(W_ih + (size_t)k * 128 * 32 + (size_t)(lane + 64) * 32);
    const float2* Whh0 = (const float2*)(W_hh + (size_t)k * 128 * 32 + (size_t)lane * 32);
    const float2* Whh1 = (const float2*)(W_hh + (size_t)k * 128 * 32 + (size_t)(lane + 64) * 32);
#pragma unroll
    for (int t = 0; t < 16; ++t) {
      float2 a = Wih0[t], c2 = Whh0[t], d2 = Wih1[t], e2 = Whh1[t];
      w0[t]      = pk_(a.x, a.y);
      w0[16 + t] = pk_(c2.x, c2.y);
      w1[t]      = pk_(d2.x, d2.y);
      w1[16 + t] = pk_(e2.x, e2.y);
    }
  }
  const float bias0 = b_ih[k * 128 + lane]      + b_hh[k * 128 + lane];
  const float bias1 = b_ih[k * 128 + lane + 64] + b_hh[k * 128 + lane + 64];
  const float rw    = rms_w[k * 32 + hl];

  float win[7]; float bi = 0.f;
  float hw0 = 0.f, hw1 = 0.f, hb0 = 0.f, hb1 = 0.f;
  if (k == 0) {
#pragma unroll
    for (int j = 0; j < 7; ++j) win[j] = W_in[hl * 7 + j];
    bi = b_in[hl];
  }
  if (k == 3) {
    hw0 = head_w[hl]; hw1 = head_w[32 + hl];
    hb0 = head_b[0];  hb1 = head_b[1];
  }

  // branchless activation constants for g1: low lanes -> tanh, high -> sigmoid
  const float mC = low ? -2.f : -1.f;
  const float aC = low ?  2.f :  1.f;
  const float dC = low ? -1.f :  0.f;

  float c  = 0.f;   // cell state (valid in low lanes)
  float hn = 0.f;
  int s_h[16];
#pragma unroll
  for (int u = 0; u < 16; ++u) s_h[u] = 0;

  const float* obs_b  = obs  + (size_t)b * S_ * OBS_;
  const float* prev_b = prev + (size_t)b * S_ * NINS_;
  float incur[7], innx[7];
  if (k == 0) {
#pragma unroll
    for (int j = 0; j < 5; ++j) incur[j] = obs_b[j];
    incur[5] = prev_b[0]; incur[6] = prev_b[1];
  }

  float* out_y  = out;                                   // [2][B][S]
  float* out_hT = out + (size_t)NINS_ * B_ * S_;         // [4][B][H]
  float* out_cT = out_hT + (size_t)NBLK_ * B_ * H_;      // [4][B][H]

  for (int tau = 0; tau < S_ + NBLK_ - 1; ++tau) {
    __syncthreads();
    const int t = tau - k;           // wave-uniform
    if (t < 0 || t >= S_) continue;

    // ---- 1. obtain xt (mirrored in both 32-lane halves) ----
    float xt;
    if (k == 0) {
      if (t + 1 < S_) {
        const float* o2 = obs_b  + (size_t)(t + 1) * OBS_;
        const float* p2 = prev_b + (size_t)(t + 1) * NINS_;
#pragma unroll
        for (int j = 0; j < 5; ++j) innx[j] = o2[j];
        innx[5] = p2[0]; innx[6] = p2[1];
      }
      float acc = bi;
#pragma unroll
      for (int j = 0; j < 7; ++j) acc = fmaf(win[j], incur[j], acc);
      xt = acc;
    } else {
      xt = slot[k - 1][tau & 1][hl];
    }

    // ---- 2. RMSNorm via DPP reduce (no LDS pipe) ----
    const float ms = half_reduce_bcast_(xt * xt);
    const float rinv = rsq_(ms * (1.0f / 32.0f) + EPS_);
    const float xn = xt * rinv * rw;

    // ---- 3. broadcast xn to SGPRs as f16 pairs (DPP pack + readlane) ----
    const half2_t pxn = pk_(xn, pairswap_(xn));  // valid at even lanes
    const int pkxi = __builtin_bit_cast(int, pxn);
    int s_x[16];
#pragma unroll
    for (int u = 0; u < 16; ++u) s_x[u] = __builtin_amdgcn_readlane(pkxi, 2 * u);

    // ---- 4. gate dots, 2-way split accumulators per output ----
    float a0 = bias0, a1 = bias1, a0b = 0.f, a1b = 0.f;
#pragma unroll
    for (int u = 0; u < 16; u += 2) {
      half2_t hx0 = __builtin_bit_cast(half2_t, s_x[u]);
      half2_t hx1 = __builtin_bit_cast(half2_t, s_x[u + 1]);
      a0  = dot2_(hx0, w0[u], a0);
      a1  = dot2_(hx0, w1[u], a1);
      a0b = dot2_(hx1, w0[u + 1], a0b);
      a1b = dot2_(hx1, w1[u + 1], a1b);
    }
#pragma unroll
    for (int u = 0; u < 16; u += 2) {
      half2_t hh0 = __builtin_bit_cast(half2_t, s_h[u]);
      half2_t hh1 = __builtin_bit_cast(half2_t, s_h[u + 1]);
      a0  = dot2_(hh0, w0[16 + u], a0);
      a1  = dot2_(hh0, w1[16 + u], a1);
      a0b = dot2_(hh1, w0[17 + u], a0b);
      a1b = dot2_(hh1, w1[17 + u], a1b);
    }
    a0 += a0b; a1 += a1b;

    // ---- 5. activations ----
    // low lane h:  a0 = i_h, a1 = g_h ; high lane: a0 = f_h, a1 = o_h
    const float g0 = rcp_(1.0f + __expf(-a0));                   // sig(i)|sig(f)
    const float g1 = fmaf(aC, rcp_(1.0f + __expf(mC * a1)), dC); // tanh(g)|sig(o)
    const float x0 = swap32_low_(g0);  // low lanes: sig(f)
    const float x1 = swap32_low_(g1);  // low lanes: sig(o)
    c = x0 * c + g0 * g1;                                        // c_new (low)
    const float tc = fmaf(2.f, rcp_(1.0f + __expf(-2.f * c)), -1.f);
    hn = x1 * tc;                                                // h_new (low)

    const float xo = xt + hn;  // residual (valid in low lanes)

    // ---- 6. handoff or head ----
    if (k < 3) {
      if (low) slot[k][(tau + 1) & 1][hl] = xo;
    } else {
      const float p0 = half_reduce_bcast_(xo * hw0) + hb0;
      const float p1 = half_reduce_bcast_(xo * hw1) + hb1;
      if (lane == 0) {
        const float v0 = fminf(__expf(fabsf(p0)) - 1.0f, 5.0f);
        const float v1 = fminf(__expf(fabsf(p1)) - 1.0f, 10.0f);
        out_y[(size_t)b * S_ + t]                   = copysignf(v0, p0);
        out_y[(size_t)B_ * S_ + (size_t)b * S_ + t] = copysignf(v1, p1);
      }
    }

    // ---- 7. repack h-state to SGPRs ----
    const half2_t phn = pk_(hn, pairswap_(hn));
    const int pkhi = __builtin_bit_cast(int, phn);
#pragma unroll
    for (int u = 0; u < 16; ++u) s_h[u] = __builtin_amdgcn_readlane(pkhi, 2 * u);

    // ---- 8. final states ----
    if (t == S_ - 1 && low) {
      out_hT[((size_t)k * B_ + b) * H_ + hl] = hn;
      out_cT[((size_t)k * B_ + b) * H_ + hl] = c;
    }

    if (k == 0) {
#pragma unroll
      for (int j = 0; j < 7; ++j) incur[j] = innx[j];
    }
  }
}

extern "C" void kernel_launch(void* const* d_in, const int* in_sizes, int n_in,
                              void* d_out, int out_size, void* d_ws, size_t ws_size,
                              hipStream_t stream) {
  (void)in_sizes; (void)n_in; (void)d_ws; (void)ws_size; (void)out_size;
  garch_pipeline_kernel<<<dim3(B_), dim3(256), 0, stream>>>(
      (const float*)d_in[0],  // obs_sequence [B,S,OBS]
      (const float*)d_in[1],  // prev_actions [B,S,NINS]
      (const float*)d_in[2],  // W_in [H, OBS+NINS]
      (const float*)d_in[3],  // b_in [H]
      (const float*)d_in[4],  // rms_w [NBLK,H]
      (const float*)d_in[5],  // W_ih [NBLK,4H,H]
      (const float*)d_in[6],  // W_hh [NBLK,4H,H]
      (const float*)d_in[7],  // b_ih [NBLK,4H]
      (const float*)d_in[8],  // b_hh [NBLK,4H]
      (const float*)d_in[9],  // head_w [NINS,H]
      (const float*)d_in[10], // head_b [NINS]
      (float*)d_out);
}

// Round 4
// 718.728 us; speedup vs baseline: 1.4253x; 1.1300x over previous
//
#include <hip/hip_runtime.h>

// PolicyNetGARCH: B=1024 S=512 OBS=5 NINS=2 H=32 NBLK=4
// 1 WG (4 waves) per batch element; wave k = LSTM block k, weights in VGPRs
// as packed f16 pairs; pipeline skew across waves; xt handoff via LDS slots.
// Round 4: 2 timesteps per barrier (super-tick), RMS rinv folded out of the
// broadcast critical path, 4 independent dot chains per step.

constexpr int B_ = 1024, S_ = 512, OBS_ = 5, NINS_ = 2, H_ = 32, NBLK_ = 4;
constexpr int TT_ = S_ / 2;   // super-ticks (2 timesteps each)
constexpr float EPS_ = 1e-6f;

typedef __fp16 half2_t __attribute__((ext_vector_type(2)));

__device__ __forceinline__ float rcp_(float x) { return __builtin_amdgcn_rcpf(x); }
__device__ __forceinline__ float rsq_(float x) { return __builtin_amdgcn_rsqf(x); }

__device__ __forceinline__ float dot2_(half2_t a, half2_t b, float c) {
  return __builtin_amdgcn_fdot2(a, b, c, false);
}
__device__ __forceinline__ half2_t pk_(float a, float b) {
  return __builtin_amdgcn_cvt_pkrtz(a, b);
}

template <int CTRL>
__device__ __forceinline__ float dppadd_(float v) {
  int m = __builtin_amdgcn_update_dpp(0, __builtin_bit_cast(int, v),
                                      CTRL, 0xF, 0xF, true);
  return v + __builtin_bit_cast(float, m);
}

// Sum over lanes 0..31, SGPR-broadcast to all lanes.
__device__ __forceinline__ float half_reduce_bcast_(float v) {
  v = dppadd_<0x111>(v);  // row_shr:1
  v = dppadd_<0x112>(v);  // row_shr:2
  v = dppadd_<0x114>(v);  // row_shr:4
  v = dppadd_<0x118>(v);  // row_shr:8
  v = dppadd_<0x142>(v);  // row_bcast:15 -> lane31 = sum(0..31)
  int s = __builtin_amdgcn_readlane(__builtin_bit_cast(int, v), 31);
  return __builtin_bit_cast(float, s);
}

// uniform 1/rms of the low-half vector (xt mirrored across halves)
__device__ __forceinline__ float rinv_of_(float xt) {
  const float ms = half_reduce_bcast_(xt * xt);
  return rsq_(ms * (1.0f / 32.0f) + EPS_);
}

// Value held by lane^32, valid in LOW lanes.
__device__ __forceinline__ float swap32_low_(float v) {
#if __has_builtin(__builtin_amdgcn_permlane32_swap)
  auto r = __builtin_amdgcn_permlane32_swap(
      __builtin_bit_cast(int, v), __builtin_bit_cast(int, v), false, false);
  return __builtin_bit_cast(float, (int)r[1]);
#else
  return __shfl_xor(v, 32);
#endif
}

// quad_perm(1,0,3,2): lane^1 exchange, 1 VALU op.
__device__ __forceinline__ float pairswap_(float v) {
  int m = __builtin_amdgcn_update_dpp(0, __builtin_bit_cast(int, v),
                                      0xB1, 0xF, 0xF, true);
  return __builtin_bit_cast(float, m);
}

// pack mirrored 32-vector (one value per low lane) into 16 SGPR f16-pairs
__device__ __forceinline__ void bcast16_(float y, int (&s)[16]) {
  const half2_t p = pk_(y, pairswap_(y));  // valid at even lanes
  const int pi = __builtin_bit_cast(int, p);
#pragma unroll
  for (int u = 0; u < 16; ++u) s[u] = __builtin_amdgcn_readlane(pi, 2 * u);
}

__global__ __launch_bounds__(256, 2) void garch_pipeline_kernel(
    const float* __restrict__ obs, const float* __restrict__ prev,
    const float* __restrict__ W_in, const float* __restrict__ b_in,
    const float* __restrict__ rms_w,
    const float* __restrict__ W_ih, const float* __restrict__ W_hh,
    const float* __restrict__ b_ih, const float* __restrict__ b_hh,
    const float* __restrict__ head_w, const float* __restrict__ head_b,
    float* __restrict__ out) {
  const int b    = blockIdx.x;
  const int tid  = threadIdx.x;
  const int k    = tid >> 6;    // wave id == LSTM block index
  const int lane = tid & 63;
  const int hl   = lane & 31;
  const bool low = (lane < 32);

  // slot[j][parity][step][h]: xt pair handoff from wave j to j+1
  __shared__ float slot[3][2][2][H_];

  half2_t w0[32], w1[32];
  {
    const float2* Wih0 = (const float2*)(W_ih + (size_t)k * 128 * 32 + (size_t)lane * 32);
    const float2* Wih1 = (const float2*)(W_ih + (size_t)k * 128 * 32 + (size_t)(lane + 64) * 32);
    const float2* Whh0 = (const float2*)(W_hh + (size_t)k * 128 * 32 + (size_t)lane * 32);
    const float2* Whh1 = (const float2*)(W_hh + (size_t)k * 128 * 32 + (size_t)(lane + 64) * 32);
#pragma unroll
    for (int t = 0; t < 16; ++t) {
      float2 a = Wih0[t], c2 = Whh0[t], d2 = Wih1[t], e2 = Whh1[t];
      w0[t]      = pk_(a.x, a.y);
      w0[16 + t] = pk_(c2.x, c2.y);
      w1[t]      = pk_(d2.x, d2.y);
      w1[16 + t] = pk_(e2.x, e2.y);
    }
  }
  const float bias0 = b_ih[k * 128 + lane]      + b_hh[k * 128 + lane];
  const float bias1 = b_ih[k * 128 + lane + 64] + b_hh[k * 128 + lane + 64];
  const float rw    = rms_w[k * 32 + hl];

  float win[7]; float bi = 0.f;
  float hw0 = 0.f, hw1 = 0.f, hb0 = 0.f, hb1 = 0.f;
  if (k == 0) {
#pragma unroll
    for (int j = 0; j < 7; ++j) win[j] = W_in[hl * 7 + j];
    bi = b_in[hl];
  }
  if (k == 3) {
    hw0 = head_w[hl]; hw1 = head_w[32 + hl];
    hb0 = head_b[0];  hb1 = head_b[1];
  }

  // branchless activation constants: low lanes -> tanh(g), high -> sigmoid(o)
  const float mC = low ? -2.f : -1.f;
  const float aC = low ?  2.f :  1.f;
  const float dC = low ? -1.f :  0.f;

  float c = 0.f, hn = 0.f;
  int s_h[16];
#pragma unroll
  for (int u = 0; u < 16; ++u) s_h[u] = 0;

  const float* obs_b  = obs  + (size_t)b * S_ * OBS_;
  const float* prev_b = prev + (size_t)b * S_ * NINS_;
  float incur[14], innx[14];   // inputs for timestep pair (A: 0..6, B: 7..13)
  if (k == 0) {
#pragma unroll
    for (int j = 0; j < 5; ++j) { incur[j] = obs_b[j]; incur[7 + j] = obs_b[5 + j]; }
    incur[5]  = prev_b[0]; incur[6]  = prev_b[1];
    incur[12] = prev_b[2]; incur[13] = prev_b[3];
  }

  float* out_y  = out;                                   // [2][B][S]
  float* out_hT = out + (size_t)NINS_ * B_ * S_;         // [4][B][H]
  float* out_cT = out_hT + (size_t)NBLK_ * B_ * H_;      // [4][B][H]

  for (int tau = 0; tau < TT_ + NBLK_ - 1; ++tau) {
    __syncthreads();
    const int tt = tau - k;          // wave-uniform super-tick index
    if (tt < 0 || tt >= TT_) continue;
    const int t0 = 2 * tt;
    const int wpar = tau & 1, rpar = (tau + 1) & 1;  // == (tau-1)&1

    // ---- 1. obtain xt pair ----
    float xtA, xtB;
    if (k == 0) {
      float accA = bi, accB = bi;
#pragma unroll
      for (int j = 0; j < 7; ++j) {
        accA = fmaf(win[j], incur[j], accA);
        accB = fmaf(win[j], incur[7 + j], accB);
      }
      xtA = accA; xtB = accB;
      if (tt + 1 < TT_) {            // prefetch next pair (off-chain)
        const float* o2 = obs_b  + (size_t)(t0 + 2) * OBS_;
        const float* p2 = prev_b + (size_t)(t0 + 2) * NINS_;
#pragma unroll
        for (int j = 0; j < 5; ++j) { innx[j] = o2[j]; innx[7 + j] = o2[5 + j]; }
        innx[5]  = p2[0]; innx[6]  = p2[1];
        innx[12] = p2[2]; innx[13] = p2[3];
      }
    } else {
      xtA = slot[k - 1][rpar][0][hl];
      xtB = slot[k - 1][rpar][1][hl];
    }

    // ---- 2. broadcasts (rinv NOT on this path) ----
    int sxA[16], sxB[16];
    bcast16_(xtA * rw, sxA);
    bcast16_(xtB * rw, sxB);
    const float rinvA = rinv_of_(xtA);   // runs in parallel with dots
    const float rinvB = rinv_of_(xtB);

    // ---- 3. step A: x-dots + h-dots (4 independent 16-deep chains) ----
    float a0x = 0.f, a1x = 0.f, a0h = bias0, a1h = bias1;
#pragma unroll
    for (int u = 0; u < 16; ++u) {
      half2_t hx = __builtin_bit_cast(half2_t, sxA[u]);
      a0x = dot2_(hx, w0[u], a0x);
      a1x = dot2_(hx, w1[u], a1x);
    }
    // step B x-dots: independent of step A entirely
    float b0x = 0.f, b1x = 0.f;
#pragma unroll
    for (int u = 0; u < 16; ++u) {
      half2_t hx = __builtin_bit_cast(half2_t, sxB[u]);
      b0x = dot2_(hx, w0[u], b0x);
      b1x = dot2_(hx, w1[u], b1x);
    }
#pragma unroll
    for (int u = 0; u < 16; ++u) {
      half2_t hh = __builtin_bit_cast(half2_t, s_h[u]);
      a0h = dot2_(hh, w0[16 + u], a0h);
      a1h = dot2_(hh, w1[16 + u], a1h);
    }
    const float a0 = fmaf(rinvA, a0x, a0h);
    const float a1 = fmaf(rinvA, a1x, a1h);

    // ---- 4. step A activations ----
    // low lane: a0=i, a1=g ; high lane: a0=f, a1=o
    {
      const float g0 = rcp_(1.0f + __expf(-a0));
      const float g1 = fmaf(aC, rcp_(1.0f + __expf(mC * a1)), dC);
      const float x0 = swap32_low_(g0);
      const float x1 = swap32_low_(g1);
      c = x0 * c + g0 * g1;
      const float tc = fmaf(2.f, rcp_(1.0f + __expf(-2.f * c)), -1.f);
      hn = x1 * tc;
    }
    const float xoA = xtA + hn;
    bcast16_(hn, s_h);

    // ---- 5. step B: h-dots with new h ----
    float b0h = bias0, b1h = bias1;
#pragma unroll
    for (int u = 0; u < 16; ++u) {
      half2_t hh = __builtin_bit_cast(half2_t, s_h[u]);
      b0h = dot2_(hh, w0[16 + u], b0h);
      b1h = dot2_(hh, w1[16 + u], b1h);
    }
    const float b0 = fmaf(rinvB, b0x, b0h);
    const float b1 = fmaf(rinvB, b1x, b1h);
    {
      const float g0 = rcp_(1.0f + __expf(-b0));
      const float g1 = fmaf(aC, rcp_(1.0f + __expf(mC * b1)), dC);
      const float x0 = swap32_low_(g0);
      const float x1 = swap32_low_(g1);
      c = x0 * c + g0 * g1;
      const float tc = fmaf(2.f, rcp_(1.0f + __expf(-2.f * c)), -1.f);
      hn = x1 * tc;
    }
    const float xoB = xtB + hn;
    bcast16_(hn, s_h);

    // ---- 6. handoff or head ----
    if (k < 3) {
      if (low) {
        slot[k][wpar][0][hl] = xoA;
        slot[k][wpar][1][hl] = xoB;
      }
    } else {
      const float p0A = half_reduce_bcast_(xoA * hw0) + hb0;
      const float p1A = half_reduce_bcast_(xoA * hw1) + hb1;
      const float p0B = half_reduce_bcast_(xoB * hw0) + hb0;
      const float p1B = half_reduce_bcast_(xoB * hw1) + hb1;
      if (lane == 0) {
        const float v0A = copysignf(fminf(__expf(fabsf(p0A)) - 1.0f, 5.0f),  p0A);
        const float v0B = copysignf(fminf(__expf(fabsf(p0B)) - 1.0f, 5.0f),  p0B);
        const float v1A = copysignf(fminf(__expf(fabsf(p1A)) - 1.0f, 10.0f), p1A);
        const float v1B = copysignf(fminf(__expf(fabsf(p1B)) - 1.0f, 10.0f), p1B);
        *(float2*)&out_y[(size_t)b * S_ + t0]                   = make_float2(v0A, v0B);
        *(float2*)&out_y[(size_t)B_ * S_ + (size_t)b * S_ + t0] = make_float2(v1A, v1B);
      }
    }

    // ---- 7. final states (t = S-1 is step B of last super-tick) ----
    if (tt == TT_ - 1 && low) {
      out_hT[((size_t)k * B_ + b) * H_ + hl] = hn;
      out_cT[((size_t)k * B_ + b) * H_ + hl] = c;
    }

    if (k == 0) {
#pragma unroll
      for (int j = 0; j < 14; ++j) incur[j] = innx[j];
    }
  }
}

extern "C" void kernel_launch(void* const* d_in, const int* in_sizes, int n_in,
                              void* d_out, int out_size, void* d_ws, size_t ws_size,
                              hipStream_t stream) {
  (void)in_sizes; (void)n_in; (void)d_ws; (void)ws_size; (void)out_size;
  garch_pipeline_kernel<<<dim3(B_), dim3(256), 0, stream>>>(
      (const float*)d_in[0],  // obs_sequence [B,S,OBS]
      (const float*)d_in[1],  // prev_actions [B,S,NINS]
      (const float*)d_in[2],  // W_in [H, OBS+NINS]
      (const float*)d_in[3],  // b_in [H]
      (const float*)d_in[4],  // rms_w [NBLK,H]
      (const float*)d_in[5],  // W_ih [NBLK,4H,H]
      (const float*)d_in[6],  // W_hh [NBLK,4H,H]
      (const float*)d_in[7],  // b_ih [NBLK,4H]
      (const float*)d_in[8],  // b_hh [NBLK,4H]
      (const float*)d_in[9],  // head_w [NINS,H]
      (const float*)d_in[10], // head_b [NINS]
      (float*)d_out);
}

// Round 5
// 701.595 us; speedup vs baseline: 1.4602x; 1.0244x over previous
//
#include <hip/hip_runtime.h>

// PolicyNetGARCH: B=1024 S=512 OBS=5 NINS=2 H=32 NBLK=4
// Round 5: one wave = one batch element, ALL 4 LSTM blocks in-wave.
// 1024 waves = 1/SIMD chip-wide. Zero barriers, zero LDS. Weights for all 4
// blocks live in VGPRs as packed f16 pairs (256 VGPRs); block-to-block
// residual is a register add. Gate weights/biases pre-scaled by log2e
// (2*log2e for tanh rows) so every activation is a raw v_exp_f32 (exp2).
// Cross-lane: DPP reduce + readlane broadcast + permlane32_swap only.

constexpr int B_ = 1024, S_ = 512, OBS_ = 5, NINS_ = 2, H_ = 32, NBLK_ = 4;
constexpr float EPS_ = 1e-6f;
constexpr float LOG2E_ = 1.4426950408889634f;

typedef __fp16 half2_t __attribute__((ext_vector_type(2)));

__device__ __forceinline__ float rcp_(float x) { return __builtin_amdgcn_rcpf(x); }
__device__ __forceinline__ float rsq_(float x) { return __builtin_amdgcn_rsqf(x); }
__device__ __forceinline__ float ex2_(float x) { return __builtin_amdgcn_exp2f(x); }

__device__ __forceinline__ float dot2_(half2_t a, half2_t b, float c) {
  return __builtin_amdgcn_fdot2(a, b, c, false);
}
__device__ __forceinline__ half2_t pk_(float a, float b) {
  return __builtin_amdgcn_cvt_pkrtz(a, b);
}

template <int CTRL>
__device__ __forceinline__ float dppadd_(float v) {
  int m = __builtin_amdgcn_update_dpp(0, __builtin_bit_cast(int, v),
                                      CTRL, 0xF, 0xF, true);
  return v + __builtin_bit_cast(float, m);
}

// Sum over lanes 0..31 (low half), SGPR-broadcast to all lanes.
__device__ __forceinline__ float half_reduce_bcast_(float v) {
  v = dppadd_<0x111>(v);  // row_shr:1
  v = dppadd_<0x112>(v);  // row_shr:2
  v = dppadd_<0x114>(v);  // row_shr:4
  v = dppadd_<0x118>(v);  // row_shr:8  -> lane15 = sum(0..15), lane31 = sum(16..31)
  v = dppadd_<0x142>(v);  // row_bcast:15 -> lane31 = sum(0..31)
  int s = __builtin_amdgcn_readlane(__builtin_bit_cast(int, v), 31);
  return __builtin_bit_cast(float, s);
}

// uniform 1/rms of the low-half 32-vector
__device__ __forceinline__ float rinv_of_(float xt) {
  const float ms = half_reduce_bcast_(xt * xt);
  return rsq_(ms * (1.0f / 32.0f) + EPS_);
}

// Value held by lane^32, valid in LOW lanes.
__device__ __forceinline__ float swap32_low_(float v) {
#if __has_builtin(__builtin_amdgcn_permlane32_swap)
  auto r = __builtin_amdgcn_permlane32_swap(
      __builtin_bit_cast(int, v), __builtin_bit_cast(int, v), false, false);
  return __builtin_bit_cast(float, (int)r[1]);
#else
  return __shfl_xor(v, 32);
#endif
}

// quad_perm(1,0,3,2): lane^1 exchange, 1 VALU op.
__device__ __forceinline__ float pairswap_(float v) {
  int m = __builtin_amdgcn_update_dpp(0, __builtin_bit_cast(int, v),
                                      0xB1, 0xF, 0xF, true);
  return __builtin_bit_cast(float, m);
}

// pack low-half 32-vector into 16 SGPR f16-pairs (broadcast)
__device__ __forceinline__ void bcast16_(float y, int (&s)[16]) {
  const half2_t p = pk_(y, pairswap_(y));  // valid at even low lanes
  const int pi = __builtin_bit_cast(int, p);
#pragma unroll
  for (int u = 0; u < 16; ++u) s[u] = __builtin_amdgcn_readlane(pi, 2 * u);
}

__global__ __launch_bounds__(64, 1) void garch_wave_kernel(
    const float* __restrict__ obs, const float* __restrict__ prev,
    const float* __restrict__ W_in, const float* __restrict__ b_in,
    const float* __restrict__ rms_w,
    const float* __restrict__ W_ih, const float* __restrict__ W_hh,
    const float* __restrict__ b_ih, const float* __restrict__ b_hh,
    const float* __restrict__ head_w, const float* __restrict__ head_b,
    float* __restrict__ out) {
  const int b    = blockIdx.x;        // block-uniform -> scalar loads for obs/prev
  const int lane = threadIdx.x;       // 0..63, one wave per WG
  const int hl   = lane & 31;
  const bool low = (lane < 32);

  // g1-path constants: low lanes -> tanh(g), high lanes -> sigmoid(o)
  const float aC = low ?  2.f : 1.f;
  const float dC = low ? -1.f : 0.f;
  const float s1 = low ? 2.f * LOG2E_ : LOG2E_;  // pre-scale for w1 rows

  // ---- weights for ALL 4 blocks, f16-packed, exp2-prescaled ----
  half2_t w0[NBLK_][32], w1[NBLK_][32];
  float bias0[NBLK_], bias1[NBLK_], rwv[NBLK_];
#pragma unroll
  for (int k = 0; k < NBLK_; ++k) {
    const float2* Wih0 = (const float2*)(W_ih + (size_t)k * 128 * 32 + (size_t)lane * 32);
    const float2* Wih1 = (const float2*)(W_ih + (size_t)k * 128 * 32 + (size_t)(lane + 64) * 32);
    const float2* Whh0 = (const float2*)(W_hh + (size_t)k * 128 * 32 + (size_t)lane * 32);
    const float2* Whh1 = (const float2*)(W_hh + (size_t)k * 128 * 32 + (size_t)(lane + 64) * 32);
#pragma unroll
    for (int t = 0; t < 16; ++t) {
      float2 a = Wih0[t], c2 = Whh0[t], d2 = Wih1[t], e2 = Whh1[t];
      w0[k][t]      = pk_(a.x * LOG2E_,  a.y * LOG2E_);   // rows lane: i|f (sigmoid)
      w0[k][16 + t] = pk_(c2.x * LOG2E_, c2.y * LOG2E_);
      w1[k][t]      = pk_(d2.x * s1,     d2.y * s1);      // rows lane+64: g|o
      w1[k][16 + t] = pk_(e2.x * s1,     e2.y * s1);
    }
    bias0[k] = (b_ih[k * 128 + lane]      + b_hh[k * 128 + lane])      * LOG2E_;
    bias1[k] = (b_ih[k * 128 + lane + 64] + b_hh[k * 128 + lane + 64]) * s1;
    rwv[k]   = rms_w[k * 32 + hl];
  }

  float win[7];
#pragma unroll
  for (int j = 0; j < 7; ++j) win[j] = W_in[hl * 7 + j];
  const float bi  = b_in[hl];
  const float hw0 = head_w[hl]      * LOG2E_;
  const float hw1 = head_w[32 + hl] * LOG2E_;
  const float hb0 = head_b[0] * LOG2E_;
  const float hb1 = head_b[1] * LOG2E_;

  float cc[NBLK_];
  int s_h[NBLK_][16];
#pragma unroll
  for (int k = 0; k < NBLK_; ++k) {
    cc[k] = 0.f;
#pragma unroll
    for (int u = 0; u < 16; ++u) s_h[k][u] = 0;
  }

  const float* obs_b  = obs  + (size_t)b * S_ * OBS_;
  const float* prev_b = prev + (size_t)b * S_ * NINS_;
  float incur[7], innx[7];
#pragma unroll
  for (int j = 0; j < 5; ++j) incur[j] = obs_b[j];
  incur[5] = prev_b[0]; incur[6] = prev_b[1];

  float* out_y  = out;                                   // [2][B][S]
  float* out_hT = out + (size_t)NINS_ * B_ * S_;         // [4][B][H]
  float* out_cT = out_hT + (size_t)NBLK_ * B_ * H_;      // [4][B][H]

  for (int t = 0; t < S_; ++t) {
    // prefetch t+1 inputs (uniform scalar loads, latency hidden by body)
    {
      const int tn = (t + 1 < S_) ? t + 1 : t;
      const float* o2 = obs_b  + (size_t)tn * OBS_;
      const float* p2 = prev_b + (size_t)tn * NINS_;
#pragma unroll
      for (int j = 0; j < 5; ++j) innx[j] = o2[j];
      innx[5] = p2[0]; innx[6] = p2[1];
    }

    // input projection (valid in low lanes; high-lane garbage unused)
    float xt = bi;
#pragma unroll
    for (int j = 0; j < 7; ++j) xt = fmaf(win[j], incur[j], xt);

#pragma unroll
    for (int k = 0; k < NBLK_; ++k) {
      // broadcast y = rw * xt (rinv folded in after the dots, off-chain)
      int s_x[16];
      bcast16_(xt * rwv[k], s_x);
      const float rinv = rinv_of_(xt);

      // 8 independent 8-deep dot chains
      float a0x = 0.f, a1x = 0.f, a0xb = 0.f, a1xb = 0.f;
#pragma unroll
      for (int u = 0; u < 16; u += 2) {
        half2_t h0 = __builtin_bit_cast(half2_t, s_x[u]);
        half2_t h1 = __builtin_bit_cast(half2_t, s_x[u + 1]);
        a0x  = dot2_(h0, w0[k][u],     a0x);
        a1x  = dot2_(h0, w1[k][u],     a1x);
        a0xb = dot2_(h1, w0[k][u + 1], a0xb);
        a1xb = dot2_(h1, w1[k][u + 1], a1xb);
      }
      float a0h = bias0[k], a1h = bias1[k], a0hb = 0.f, a1hb = 0.f;
#pragma unroll
      for (int u = 0; u < 16; u += 2) {
        half2_t h0 = __builtin_bit_cast(half2_t, s_h[k][u]);
        half2_t h1 = __builtin_bit_cast(half2_t, s_h[k][u + 1]);
        a0h  = dot2_(h0, w0[k][16 + u], a0h);
        a1h  = dot2_(h0, w1[k][16 + u], a1h);
        a0hb = dot2_(h1, w0[k][17 + u], a0hb);
        a1hb = dot2_(h1, w1[k][17 + u], a1hb);
      }
      const float a0 = fmaf(rinv, a0x + a0xb, a0h + a0hb);  // log2e-scaled gates
      const float a1 = fmaf(rinv, a1x + a1xb, a1h + a1hb);

      // activations in exp2 domain
      // low lane: a0=i, a1=g ; high lane: a0=f, a1=o
      const float g0 = rcp_(1.0f + ex2_(-a0));                 // sig(i)|sig(f)
      const float g1 = fmaf(aC, rcp_(1.0f + ex2_(-a1)), dC);   // tanh(g)|sig(o)
      const float x0 = swap32_low_(g0);  // low: sig(f)
      const float x1 = swap32_low_(g1);  // low: sig(o)
      cc[k] = x0 * cc[k] + g0 * g1;                            // c_new (low)
      const float tc = fmaf(2.f, rcp_(1.0f + ex2_(-2.f * LOG2E_ * cc[k])), -1.f);
      const float hnv = x1 * tc;                               // h_new (low)

      xt += hnv;                    // residual, register handoff to next block
      bcast16_(hnv, s_h[k]);

      if (t == S_ - 1 && low) {
        out_hT[((size_t)k * B_ + b) * H_ + hl] = hnv;
        out_cT[((size_t)k * B_ + b) * H_ + hl] = cc[k];
      }
    }

    // head + symexp (exp2 domain; log2e pre-folded into hw/hb)
    const float p0 = half_reduce_bcast_(xt * hw0) + hb0;
    const float p1 = half_reduce_bcast_(xt * hw1) + hb1;
    const float v0 = copysignf(fminf(ex2_(fabsf(p0)) - 1.0f, 5.0f),  p0);
    const float v1 = copysignf(fminf(ex2_(fabsf(p1)) - 1.0f, 10.0f), p1);
    if (lane == 0) {
      out_y[(size_t)b * S_ + t]                   = v0;
      out_y[(size_t)B_ * S_ + (size_t)b * S_ + t] = v1;
    }

#pragma unroll
    for (int j = 0; j < 7; ++j) incur[j] = innx[j];
  }
}

extern "C" void kernel_launch(void* const* d_in, const int* in_sizes, int n_in,
                              void* d_out, int out_size, void* d_ws, size_t ws_size,
                              hipStream_t stream) {
  (void)in_sizes; (void)n_in; (void)d_ws; (void)ws_size; (void)out_size;
  garch_wave_kernel<<<dim3(B_), dim3(64), 0, stream>>>(
      (const float*)d_in[0],  // obs_sequence [B,S,OBS]
      (const float*)d_in[1],  // prev_actions [B,S,NINS]
      (const float*)d_in[2],  // W_in [H, OBS+NINS]
      (const float*)d_in[3],  // b_in [H]
      (const float*)d_in[4],  // rms_w [NBLK,H]
      (const float*)d_in[5],  // W_ih [NBLK,4H,H]
      (const float*)d_in[6],  // W_hh [NBLK,4H,H]
      (const float*)d_in[7],  // b_ih [NBLK,4H]
      (const float*)d_in[8],  // b_hh [NBLK,4H]
      (const float*)d_in[9],  // head_w [NINS,H]
      (const float*)d_in[10], // head_b [NINS]
      (float*)d_out);
}